// Round 1
// baseline (6241.628 us; speedup 1.0000x reference)
//
#include <hip/hip_runtime.h>

#define TMAX 8192
#define H 128

__device__ __forceinline__ float sigf(float x)       { return 1.f / (1.f + __expf(-x)); }
__device__ __forceinline__ float tanhf_fast(float x) { return 2.f / (1.f + __expf(-2.f * x)) - 1.f; }

// One block, 512 threads = 8 waves (2/SIMD).
// Thread t: h-element j = t>>2, k-quarter q = t&3.
// Each thread holds all 4 gate rows {j, j+128, j+256, j+384} x 32-wide k-slice:
//   128 weight floats in VGPRs, 128 FMAs/step, 8 broadcast ds_read_b128 of h.
// Cross-quarter reduce: 2-round shfl_xor butterfly (intra-wave, no LDS round-trip).
// All 4 lanes of a group redundantly run the activations -> ONE barrier per step.
// h kept interleaved in LDS (slot i*4+q) so the 4 q-groups hit disjoint banks.
__global__ __launch_bounds__(512, 2)
void lstm_seq_kernel(const float* __restrict__ x,
                     const float* __restrict__ Wih,
                     const float* __restrict__ Whh,
                     const float* __restrict__ bih,
                     const float* __restrict__ bhh,
                     const float* __restrict__ Wlin,
                     const float* __restrict__ blin,
                     const float* __restrict__ h0,
                     const float* __restrict__ c0,
                     float* __restrict__ out,
                     int T)
{
    __shared__ float  x_s[TMAX];      // 32 KB
    __shared__ float4 h_il[H / 4];    // interleaved h: slot i*4+q = h[q*32 + i*4 .. +3]

    const int t = threadIdx.x;        // 0..511
    const int j = t >> 2;             // h element 0..127
    const int q = t & 3;              // k-quarter

    // Stage input sequence (one-time, coalesced).
    for (int idx = t; idx < T; idx += 512) x_s[idx] = x[idx];

    // Weights for 4 gate rows x quarter q: 32 float4 = 128 VGPRs.
    float4 wi[8], wf[8], wg[8], wo[8];
    {
        const float4* pi = (const float4*)(Whh + (j      ) * H + q * 32);
        const float4* pf = (const float4*)(Whh + (j + 128) * H + q * 32);
        const float4* pg = (const float4*)(Whh + (j + 256) * H + q * 32);
        const float4* po = (const float4*)(Whh + (j + 384) * H + q * 32);
        #pragma unroll
        for (int i = 0; i < 8; ++i) { wi[i] = pi[i]; wf[i] = pf[i]; wg[i] = pg[i]; wo[i] = po[i]; }
    }

    // x-weight and bias only contribute through quarter 0's partial.
    const bool lead = (q == 0);
    const float wxi = lead ? Wih[j      ] : 0.f;
    const float wxf = lead ? Wih[j + 128] : 0.f;
    const float wxg = lead ? Wih[j + 256] : 0.f;
    const float wxo = lead ? Wih[j + 384] : 0.f;
    const float bi_ = lead ? bih[j      ] + bhh[j      ] : 0.f;
    const float bf_ = lead ? bih[j + 128] + bhh[j + 128] : 0.f;
    const float bg_ = lead ? bih[j + 256] + bhh[j + 256] : 0.f;
    const float bo_ = lead ? bih[j + 384] + bhh[j + 384] : 0.f;

    float c = c0[j];                  // replicated across the 4 lanes of a group

    // h0 -> interleaved LDS.
    if (t < H) {
        const int fi = ((t >> 2) & 7) * 16 + (t >> 5) * 4 + (t & 3);
        ((float*)h_il)[fi] = h0[t];
    }
    // My h-write slot (linear j -> interleaved float index).
    const int widx = ((j >> 2) & 7) * 16 + (j >> 5) * 4 + (j & 3);
    __syncthreads();

    for (int step = 0; step < T; ++step) {
        const float xv = x_s[step];   // broadcast
        float ai0 = fmaf(xv, wxi, bi_), ai1 = 0.f;
        float af0 = fmaf(xv, wxf, bf_), af1 = 0.f;
        float ag0 = fmaf(xv, wxg, bg_), ag1 = 0.f;
        float ao0 = fmaf(xv, wxo, bo_), ao1 = 0.f;
        #pragma unroll
        for (int i = 0; i < 8; ++i) {
            const float4 h4 = h_il[i * 4 + q];  // 16-lane broadcast, q-groups on disjoint banks
            ai0 = fmaf(wi[i].x, h4.x, ai0); ai1 = fmaf(wi[i].y, h4.y, ai1);
            ai0 = fmaf(wi[i].z, h4.z, ai0); ai1 = fmaf(wi[i].w, h4.w, ai1);
            af0 = fmaf(wf[i].x, h4.x, af0); af1 = fmaf(wf[i].y, h4.y, af1);
            af0 = fmaf(wf[i].z, h4.z, af0); af1 = fmaf(wf[i].w, h4.w, af1);
            ag0 = fmaf(wg[i].x, h4.x, ag0); ag1 = fmaf(wg[i].y, h4.y, ag1);
            ag0 = fmaf(wg[i].z, h4.z, ag0); ag1 = fmaf(wg[i].w, h4.w, ag1);
            ao0 = fmaf(wo[i].x, h4.x, ao0); ao1 = fmaf(wo[i].y, h4.y, ao1);
            ao0 = fmaf(wo[i].z, h4.z, ao0); ao1 = fmaf(wo[i].w, h4.w, ao1);
        }
        float ai = ai0 + ai1;
        float af = af0 + af1;
        float ag = ag0 + ag1;
        float ao = ao0 + ao1;

        // Sum the 4 k-quarter partials inside the wave (lanes 4j..4j+3).
        ai += __shfl_xor(ai, 1); ai += __shfl_xor(ai, 2);
        af += __shfl_xor(af, 1); af += __shfl_xor(af, 2);
        ag += __shfl_xor(ag, 1); ag += __shfl_xor(ag, 2);
        ao += __shfl_xor(ao, 1); ao += __shfl_xor(ao, 2);

        // All 4 lanes compute identically (keeps c replicated, no divergence).
        const float ig  = sigf(ai);
        const float fg  = sigf(af);
        const float gg2 = tanhf_fast(ag);
        const float og  = sigf(ao);
        c = fmaf(fg, c, ig * gg2);
        const float hn = og * tanhf_fast(c);
        if (lead) ((float*)h_il)[widx] = hn;   // 16 lanes/wave, distinct banks
        __syncthreads();                        // the only barrier per step
    }

    // Final linear: out = dot(W_lin, h_T) + b_lin (wave 0).
    if (t < 64) {
        const float* hf = (const float*)h_il;
        const int i0 = ((t >> 2) & 7) * 16 + (t >> 5) * 4 + (t & 3);
        const int t2 = t + 64;
        const int i1 = ((t2 >> 2) & 7) * 16 + (t2 >> 5) * 4 + (t2 & 3);
        float v = Wlin[t] * hf[i0] + Wlin[t2] * hf[i1];
        #pragma unroll
        for (int off = 32; off >= 1; off >>= 1) v += __shfl_down(v, off);
        if (t == 0) out[0] = v + blin[0];
    }
}

extern "C" void kernel_launch(void* const* d_in, const int* in_sizes, int n_in,
                              void* d_out, int out_size, void* d_ws, size_t ws_size,
                              hipStream_t stream) {
    const float* x    = (const float*)d_in[0];
    const float* Wih  = (const float*)d_in[1];
    const float* Whh  = (const float*)d_in[2];
    const float* bih  = (const float*)d_in[3];
    const float* bhh  = (const float*)d_in[4];
    const float* Wlin = (const float*)d_in[5];
    const float* blin = (const float*)d_in[6];
    const float* h0   = (const float*)d_in[7];
    const float* c0   = (const float*)d_in[8];
    float* out = (float*)d_out;
    const int T = in_sizes[0];

    lstm_seq_kernel<<<1, 512, 0, stream>>>(x, Wih, Whh, bih, bhh, Wlin, blin,
                                           h0, c0, out, T);
}